// Round 1
// 1622.114 us; speedup vs baseline: 1.4069x; 1.4069x over previous
//
#include <hip/hip_runtime.h>

#define S 1024
#define D 768
#define NH 12
#define HD 64
#define DFF 3072
#define NL 4

typedef unsigned short u16;
typedef __attribute__((ext_vector_type(8))) short bf8;
typedef __attribute__((ext_vector_type(4))) float f32x4;

__device__ __forceinline__ float b2f(u16 h){ return __uint_as_float(((unsigned)h)<<16); }
__device__ __forceinline__ u16 f2b(float f){
  unsigned u = __float_as_uint(f);
  return (u16)((u + 0x7fffu + ((u>>16)&1u)) >> 16);   // round-to-nearest-even
}

// ---------------- fp32 -> bf16 convert ----------------
__global__ __launch_bounds__(256) void cvt_kernel(const float* __restrict__ in, u16* __restrict__ out, int n){
  int i = (blockIdx.x*256 + threadIdx.x)*4;
  if (i >= n) return;
  float4 v = *(const float4*)(in + i);
  ushort4 o; o.x=f2b(v.x); o.y=f2b(v.y); o.z=f2b(v.z); o.w=f2b(v.w);
  *(ushort4*)(out+i) = o;
}

// pack Wq/Wk/Wv into one (L,2304,768) bf16 matrix
__global__ __launch_bounds__(256) void pack_qkv_kernel(const float* __restrict__ Wq, const float* __restrict__ Wk,
                                                       const float* __restrict__ Wv, u16* __restrict__ dst){
  const int per_layer = 2304*D;
  int i = (blockIdx.x*256 + threadIdx.x)*4;
  if (i >= NL*per_layer) return;
  int l = i / per_layer; int rem = i - l*per_layer;
  int r = rem / D, c = rem - r*D;
  const float* src;
  if (r < 768)       src = Wq + (size_t)l*D*D + (size_t)r*D + c;
  else if (r < 1536) src = Wk + (size_t)l*D*D + (size_t)(r-768)*D + c;
  else               src = Wv + (size_t)l*D*D + (size_t)(r-1536)*D + c;
  float4 v = *(const float4*)src;
  ushort4 o; o.x=f2b(v.x); o.y=f2b(v.y); o.z=f2b(v.z); o.w=f2b(v.w);
  *(ushort4*)(dst+i) = o;
}

// Rsum = rel_pos + rel_2d_pos + rel_2d_angle  (bf16 out), 8 elems/thread
__global__ __launch_bounds__(256) void rsum_kernel(const float* __restrict__ a, const float* __restrict__ b,
                                                   const float* __restrict__ c, u16* __restrict__ out){
  size_t i = ((size_t)blockIdx.x*256 + threadIdx.x)*8;
  float4 a0 = *(const float4*)(a+i), a1 = *(const float4*)(a+i+4);
  float4 b0 = *(const float4*)(b+i), b1 = *(const float4*)(b+i+4);
  float4 c0 = *(const float4*)(c+i), c1 = *(const float4*)(c+i+4);
  ushort4 o0, o1;
  o0.x=f2b(a0.x+b0.x+c0.x); o0.y=f2b(a0.y+b0.y+c0.y); o0.z=f2b(a0.z+b0.z+c0.z); o0.w=f2b(a0.w+b0.w+c0.w);
  o1.x=f2b(a1.x+b1.x+c1.x); o1.y=f2b(a1.y+b1.y+c1.y); o1.z=f2b(a1.z+b1.z+c1.z); o1.w=f2b(a1.w+b1.w+c1.w);
  *(ushort4*)(out+i)   = o0;
  *(ushort4*)(out+i+4) = o1;
}

// ---------------- generic bf16 MFMA GEMM: C[m,n] = sum_k A[m,k]*B[n,k] ----------------
// MODE 0: QKV epilogue (q scaled bf16 head layout, k bf16 head layout, v bf16 TRANSPOSED [n][hd][s])
// MODE 1: +bias +res -> fp32 out (stride 768)
// MODE 2: gelu(+bias) -> bf16 out (stride 3072)
template<int MODE>
__global__ __launch_bounds__(256) void gemm_kernel(
    const u16* __restrict__ A, const u16* __restrict__ B, int K,
    const float* __restrict__ bias0, const float* __restrict__ bias1, const float* __restrict__ bias2,
    const float* __restrict__ res, float* __restrict__ outf, u16* __restrict__ outb,
    u16* __restrict__ qo, u16* __restrict__ ko, u16* __restrict__ vto)
{
  int w = threadIdx.x >> 6, lane = threadIdx.x & 63;
  int quad = lane >> 4, l16 = lane & 15;
  int m0 = blockIdx.x*64 + (w&1)*32;
  int n0 = blockIdx.y*64 + (w>>1)*32;
  const u16* pa = A + (size_t)(m0 + l16)*K + quad*8;
  const u16* pb = B + (size_t)(n0 + l16)*K + quad*8;
  const size_t a16 = (size_t)16*K, b16 = (size_t)16*K;

  f32x4 accs[2][2];
  #pragma unroll
  for (int i=0;i<2;i++)
    #pragma unroll
    for (int j=0;j<2;j++){ accs[i][j][0]=0.f; accs[i][j][1]=0.f; accs[i][j][2]=0.f; accs[i][j][3]=0.f; }

  bf8 a0 = *(const bf8*)pa,        a1 = *(const bf8*)(pa + a16);
  bf8 b0 = *(const bf8*)pb,        b1 = *(const bf8*)(pb + b16);
  for (int k0 = 32; k0 < K; k0 += 32){
    bf8 na0 = *(const bf8*)(pa + k0), na1 = *(const bf8*)(pa + a16 + k0);
    bf8 nb0 = *(const bf8*)(pb + k0), nb1 = *(const bf8*)(pb + b16 + k0);
    accs[0][0] = __builtin_amdgcn_mfma_f32_16x16x32_bf16(a0,b0,accs[0][0],0,0,0);
    accs[0][1] = __builtin_amdgcn_mfma_f32_16x16x32_bf16(a0,b1,accs[0][1],0,0,0);
    accs[1][0] = __builtin_amdgcn_mfma_f32_16x16x32_bf16(a1,b0,accs[1][0],0,0,0);
    accs[1][1] = __builtin_amdgcn_mfma_f32_16x16x32_bf16(a1,b1,accs[1][1],0,0,0);
    a0=na0; a1=na1; b0=nb0; b1=nb1;
  }
  accs[0][0] = __builtin_amdgcn_mfma_f32_16x16x32_bf16(a0,b0,accs[0][0],0,0,0);
  accs[0][1] = __builtin_amdgcn_mfma_f32_16x16x32_bf16(a0,b1,accs[0][1],0,0,0);
  accs[1][0] = __builtin_amdgcn_mfma_f32_16x16x32_bf16(a1,b0,accs[1][0],0,0,0);
  accs[1][1] = __builtin_amdgcn_mfma_f32_16x16x32_bf16(a1,b1,accs[1][1],0,0,0);

  // C/D layout: col = lane&15 (n), row = quad*4 + reg (m)
  if (MODE == 0){
    if (n0 < 1536){
      #pragma unroll
      for (int i=0;i<2;i++)
        #pragma unroll
        for (int j=0;j<2;j++)
          #pragma unroll
          for (int r=0;r<4;r++){
            int m = m0 + i*16 + quad*4 + r;
            int n = n0 + j*16 + l16;
            float val = accs[i][j][r];
            if (n < 768){
              val += bias0[n];
              qo[((size_t)(n>>6)*S + m)*HD + (n&63)] = f2b(val*0.125f);
            } else {
              int nn = n - 768; val += bias1[nn];
              ko[((size_t)(nn>>6)*S + m)*HD + (nn&63)] = f2b(val);
            }
          }
    } else {
      // V transposed: vto[(head*HD + hd)*S + m], m = 4 consecutive rows per lane
      #pragma unroll
      for (int i=0;i<2;i++)
        #pragma unroll
        for (int j=0;j<2;j++){
          int nn = n0 + j*16 + l16 - 1536;
          float b = bias2[nn];
          ushort4 o;
          o.x = f2b(accs[i][j][0]+b);
          o.y = f2b(accs[i][j][1]+b);
          o.z = f2b(accs[i][j][2]+b);
          o.w = f2b(accs[i][j][3]+b);
          *(ushort4*)(vto + ((size_t)(nn>>6)*HD + (nn&63))*S + m0 + i*16 + quad*4) = o;
        }
    }
  } else {
    #pragma unroll
    for (int i=0;i<2;i++){
      #pragma unroll
      for (int j=0;j<2;j++){
        #pragma unroll
        for (int r=0;r<4;r++){
          int m = m0 + i*16 + quad*4 + r;
          int n = n0 + j*16 + l16;
          float val = accs[i][j][r];
          if (MODE == 1){
            val += bias0[n] + res[(size_t)m*768 + n];
            outf[(size_t)m*768 + n] = val;
          } else {
            val += bias0[n];
            float g = 0.5f*val*(1.0f + erff(val*0.70710678118f));
            outb[(size_t)m*DFF + n] = f2b(g);
          }
        }
      }
    }
  }
}

// ---------------- LayerNorm: block per row ----------------
__global__ __launch_bounds__(256) void ln_kernel(const float* __restrict__ in, const float* __restrict__ g,
                                                 const float* __restrict__ bb, float* __restrict__ outf,
                                                 u16* __restrict__ outb){
  int row = blockIdx.x, t = threadIdx.x;
  int w = t>>6, lane = t&63;
  const float* x = in + (size_t)row*D;
  float v0 = x[t], v1 = x[t+256], v2 = x[t+512];
  float s = v0+v1+v2;
  #pragma unroll
  for (int m=32;m;m>>=1) s += __shfl_xor(s, m);
  __shared__ float red[8];
  if (lane==0) red[w] = s;
  __syncthreads();
  float mu = (red[0]+red[1]+red[2]+red[3]) * (1.0f/768.0f);
  float d0=v0-mu, d1=v1-mu, d2=v2-mu;
  float s2 = d0*d0+d1*d1+d2*d2;
  #pragma unroll
  for (int m=32;m;m>>=1) s2 += __shfl_xor(s2, m);
  if (lane==0) red[4+w] = s2;
  __syncthreads();
  float var = (red[4]+red[5]+red[6]+red[7]) * (1.0f/768.0f);
  float rs = rsqrtf(var + 1e-12f);
  float y0 = d0*rs*g[t]     + bb[t];
  float y1 = d1*rs*g[t+256] + bb[t+256];
  float y2 = d2*rs*g[t+512] + bb[t+512];
  size_t base = (size_t)row*D;
  outf[base+t]=y0; outf[base+t+256]=y1; outf[base+t+512]=y2;
  outb[base+t]=f2b(y0); outb[base+t+256]=f2b(y1); outb[base+t+512]=f2b(y2);
}

// ---------------- s1: scoresR[n,s,k] = q[n,s]·Rsum[s,k]  via MFMA ----------------
// block = one s; A = q all heads (12 rows, pad 16), B = Rsum[s] (1024x64), single-pass stream.
__global__ __launch_bounds__(256) void s1_kernel(const u16* __restrict__ qb, const u16* __restrict__ R,
                                                 u16* __restrict__ sr){
  int s = blockIdx.x, t = threadIdx.x;
  int w = t>>6, lane = t&63, quad = lane>>4, l16 = lane&15;
  int h = (l16 < NH) ? l16 : 0;                 // pad heads 12..15 (results discarded)
  const u16* qrow = qb + ((size_t)h*S + s)*HD + quad*8;
  bf8 a_lo = *(const bf8*)qrow;
  bf8 a_hi = *(const bf8*)(qrow + 32);
  const u16* Rbase = R + (size_t)s*S*HD;
  u16* srs = sr + ((size_t)s<<10);
  #pragma unroll 4
  for (int nt = w; nt < 64; nt += 4){
    const u16* rp = Rbase + (size_t)(nt*16 + l16)*HD + quad*8;
    bf8 b_lo = *(const bf8*)rp;
    bf8 b_hi = *(const bf8*)(rp + 32);
    f32x4 acc; acc[0]=0.f; acc[1]=0.f; acc[2]=0.f; acc[3]=0.f;
    acc = __builtin_amdgcn_mfma_f32_16x16x32_bf16(a_lo,b_lo,acc,0,0,0);
    acc = __builtin_amdgcn_mfma_f32_16x16x32_bf16(a_hi,b_hi,acc,0,0,0);
    int k = nt*16 + l16;
    #pragma unroll
    for (int r=0;r<4;r++){
      int head = quad*4 + r;
      if (head < NH)
        srs[((size_t)head<<20) + k] = f2b(acc[r]);
    }
  }
}

// ---------------- s2: flash attention, all-MFMA ----------------
// block = 16 q-rows x 1 head, 4 waves split k 4-way, online softmax, LDS merge.
__global__ __launch_bounds__(256) void s2_kernel(const u16* __restrict__ qb, const u16* __restrict__ kb,
                                                 const u16* __restrict__ vt, const u16* __restrict__ sr,
                                                 const float* __restrict__ mask, u16* __restrict__ ctx){
  constexpr int PS = 72;                         // padded P row stride (u16) -> <=2-way LDS conflicts
  __shared__ u16   pbuf[4][16*PS];
  __shared__ float obuf[4][16][65];
  __shared__ float mlbuf[4][2][16];
  int n = blockIdx.y, s0 = blockIdx.x*16;
  int w = threadIdx.x>>6, lane = threadIdx.x&63, quad = lane>>4, l16 = lane&15;

  const u16* qrow = qb + ((size_t)n*S + s0 + l16)*HD + quad*8;
  bf8 a_lo = *(const bf8*)qrow;
  bf8 a_hi = *(const bf8*)(qrow + 32);
  const u16* kbase  = kb + (size_t)n*S*HD;
  const u16* vbase  = vt + (size_t)n*HD*S;
  const u16* srbase = sr + ((size_t)n<<20) + ((size_t)s0<<10);

  float m_run[4], l_run[4];
  f32x4 acc_o[4];
  #pragma unroll
  for (int r=0;r<4;r++){ m_run[r] = -1e30f; l_run[r] = 0.f; }
  #pragma unroll
  for (int jh=0;jh<4;jh++){ acc_o[jh][0]=0.f; acc_o[jh][1]=0.f; acc_o[jh][2]=0.f; acc_o[jh][3]=0.f; }

  u16* pw = &pbuf[w][0];

  for (int kt = w*64; kt < S; kt += 256){
    // ---- QK^T (4 x 16-col subtiles) ----
    f32x4 sc[4];
    #pragma unroll
    for (int j=0;j<4;j++){
      const u16* kp = kbase + (size_t)(kt + j*16 + l16)*HD + quad*8;
      bf8 b_lo = *(const bf8*)kp;
      bf8 b_hi = *(const bf8*)(kp + 32);
      f32x4 a; a[0]=0.f; a[1]=0.f; a[2]=0.f; a[3]=0.f;
      a = __builtin_amdgcn_mfma_f32_16x16x32_bf16(a_lo,b_lo,a,0,0,0);
      a = __builtin_amdgcn_mfma_f32_16x16x32_bf16(a_hi,b_hi,a,0,0,0);
      sc[j]=a;
    }
    // ---- add rel scores + mask ----
    float sv[4][4];
    #pragma unroll
    for (int j=0;j<4;j++){
      int k = kt + j*16 + l16;
      float mk = mask[k];
      #pragma unroll
      for (int r=0;r<4;r++)
        sv[j][r] = sc[j][r] + b2f(srbase[((size_t)(quad*4+r)<<10) + k]) + mk;
    }
    // ---- online softmax update (rows quad*4+r live across the quad's 16 lanes) ----
    #pragma unroll
    for (int r=0;r<4;r++){
      float mx = fmaxf(fmaxf(sv[0][r],sv[1][r]),fmaxf(sv[2][r],sv[3][r]));
      #pragma unroll
      for (int mm=8;mm;mm>>=1) mx = fmaxf(mx, __shfl_xor(mx, mm));
      float m_new = fmaxf(m_run[r], mx);
      float f = __expf(m_run[r] - m_new);
      float ps = 0.f;
      #pragma unroll
      for (int j=0;j<4;j++){ float p = __expf(sv[j][r]-m_new); sv[j][r]=p; ps += p; }
      #pragma unroll
      for (int mm=8;mm;mm>>=1) ps += __shfl_xor(ps, mm);
      l_run[r] = l_run[r]*f + ps;
      m_run[r] = m_new;
      #pragma unroll
      for (int jh=0;jh<4;jh++) acc_o[jh][r] *= f;
    }
    // ---- stage P (bf16) to per-wave LDS for fragment transpose ----
    #pragma unroll
    for (int j=0;j<4;j++)
      #pragma unroll
      for (int r=0;r<4;r++)
        pw[(quad*4+r)*PS + j*16 + l16] = f2b(sv[j][r]);
    asm volatile("s_waitcnt lgkmcnt(0)" ::: "memory");   // wave-local RAW through LDS
    bf8 p_lo = *(const bf8*)(pw + l16*PS + quad*8);
    bf8 p_hi = *(const bf8*)(pw + l16*PS + 32 + quad*8);
    // ---- PV via MFMA (B = V^T rows) ----
    #pragma unroll
    for (int jh=0;jh<4;jh++){
      const u16* vp = vbase + (size_t)(jh*16 + l16)*S + kt + quad*8;
      bf8 v_lo = *(const bf8*)vp;
      bf8 v_hi = *(const bf8*)(vp + 32);
      acc_o[jh] = __builtin_amdgcn_mfma_f32_16x16x32_bf16(p_lo,v_lo,acc_o[jh],0,0,0);
      acc_o[jh] = __builtin_amdgcn_mfma_f32_16x16x32_bf16(p_hi,v_hi,acc_o[jh],0,0,0);
    }
  }
  // ---- write partials, merge 4 k-splits ----
  #pragma unroll
  for (int jh=0;jh<4;jh++)
    #pragma unroll
    for (int r=0;r<4;r++)
      obuf[w][quad*4+r][jh*16+l16] = acc_o[jh][r];
  if (l16 == 0){
    #pragma unroll
    for (int r=0;r<4;r++){
      mlbuf[w][0][quad*4+r] = m_run[r];
      mlbuf[w][1][quad*4+r] = l_run[r];
    }
  }
  __syncthreads();
  int col = w*16 + l16;                           // wave w merges its 16-col group
  #pragma unroll
  for (int r=0;r<4;r++){
    int row = quad*4 + r;
    float ma = mlbuf[0][0][row], mb = mlbuf[1][0][row], mc = mlbuf[2][0][row], md = mlbuf[3][0][row];
    float mg = fmaxf(fmaxf(ma,mb),fmaxf(mc,md));
    float fa = __expf(ma-mg), fb = __expf(mb-mg), fc = __expf(mc-mg), fd = __expf(md-mg);
    float lg = mlbuf[0][1][row]*fa + mlbuf[1][1][row]*fb + mlbuf[2][1][row]*fc + mlbuf[3][1][row]*fd;
    float o  = obuf[0][row][col]*fa + obuf[1][row][col]*fb + obuf[2][row][col]*fc + obuf[3][row][col]*fd;
    ctx[(size_t)(s0 + row)*D + (size_t)n*HD + col] = f2b(o / lg);
  }
}

extern "C" void kernel_launch(void* const* d_in, const int* in_sizes, int n_in,
                              void* d_out, int out_size, void* d_ws, size_t ws_size,
                              hipStream_t stream) {
  (void)in_sizes; (void)n_in; (void)out_size; (void)ws_size;
  const float* hidden=(const float*)d_in[0];
  const float* amask =(const float*)d_in[1];
  const float* rel   =(const float*)d_in[2];
  const float* rel2  =(const float*)d_in[3];
  const float* rela  =(const float*)d_in[4];
  const float* Wq=(const float*)d_in[5];  const float* bq=(const float*)d_in[6];
  const float* Wk=(const float*)d_in[7];  const float* bk=(const float*)d_in[8];
  const float* Wv=(const float*)d_in[9];  const float* bv=(const float*)d_in[10];
  const float* Wo=(const float*)d_in[11]; const float* bo=(const float*)d_in[12];
  const float* g1=(const float*)d_in[13]; const float* be1=(const float*)d_in[14];
  const float* Wi=(const float*)d_in[15]; const float* bi=(const float*)d_in[16];
  const float* Wo2=(const float*)d_in[17];const float* bo2=(const float*)d_in[18];
  const float* g2=(const float*)d_in[19]; const float* be2=(const float*)d_in[20];

  char* wsp = (char*)d_ws; size_t off = 0;
  auto take = [&](size_t bytes)->char* { char* p = wsp + off; off += (bytes + 255) & ~(size_t)255; return p; };
  u16*   RS   = (u16*)  take((size_t)S*S*HD*2);      // 128 MB bf16 Rsum
  u16*   WQKV = (u16*)  take((size_t)NL*2304*D*2);
  u16*   WOb  = (u16*)  take((size_t)NL*D*D*2);
  u16*   WIb  = (u16*)  take((size_t)NL*DFF*D*2);
  u16*   WO2b = (u16*)  take((size_t)NL*D*DFF*2);
  u16*   HBF  = (u16*)  take((size_t)S*D*2);
  u16*   QB   = (u16*)  take((size_t)NH*S*HD*2);
  u16*   KB   = (u16*)  take((size_t)NH*S*HD*2);
  u16*   VT   = (u16*)  take((size_t)NH*HD*S*2);     // V transposed bf16 [n][hd][s]
  u16*   SR   = (u16*)  take((size_t)NH*S*S*2);      // 24 MB bf16 rel-scores
  u16*   CTXB = (u16*)  take((size_t)S*D*2);
  float* TMP  = (float*)take((size_t)S*D*4);
  float* ATT  = (float*)take((size_t)S*D*4);
  u16*   ATTB = (u16*)  take((size_t)S*D*2);
  u16*   INTB = (u16*)  take((size_t)S*DFF*2);
  float* HBUF = (float*)take((size_t)S*D*4);

  // one-time conversions
  pack_qkv_kernel<<<dim3(6912),256,0,stream>>>(Wq, Wk, Wv, WQKV);
  cvt_kernel<<<dim3(2304),256,0,stream>>>(Wo,  WOb,  NL*D*D);
  cvt_kernel<<<dim3(9216),256,0,stream>>>(Wi,  WIb,  NL*DFF*D);
  cvt_kernel<<<dim3(9216),256,0,stream>>>(Wo2, WO2b, NL*D*DFF);
  cvt_kernel<<<dim3(768), 256,0,stream>>>(hidden, HBF, S*D);
  rsum_kernel<<<dim3(32768),256,0,stream>>>(rel, rel2, rela, RS);

  const float* hres = hidden;
  for (int l=0;l<NL;l++){
    gemm_kernel<0><<<dim3(16,36),256,0,stream>>>(HBF, WQKV + (size_t)l*2304*D, D,
        bq + l*D, bk + l*D, bv + l*D, nullptr, nullptr, nullptr, QB, KB, VT);
    s1_kernel<<<dim3(1024),256,0,stream>>>(QB, RS, SR);
    s2_kernel<<<dim3(64,NH),256,0,stream>>>(QB, KB, VT, SR, amask, CTXB);
    gemm_kernel<1><<<dim3(16,12),256,0,stream>>>(CTXB, WOb + (size_t)l*D*D, D,
        bo + l*D, nullptr, nullptr, hres, TMP, nullptr, nullptr, nullptr, nullptr);
    ln_kernel<<<dim3(1024),256,0,stream>>>(TMP, g1 + l*D, be1 + l*D, ATT, ATTB);
    gemm_kernel<2><<<dim3(16,48),256,0,stream>>>(ATTB, WIb + (size_t)l*DFF*D, D,
        bi + l*DFF, nullptr, nullptr, nullptr, nullptr, INTB, nullptr, nullptr, nullptr);
    gemm_kernel<1><<<dim3(16,12),256,0,stream>>>(INTB, WO2b + (size_t)l*D*DFF, DFF,
        bo2 + l*D, nullptr, nullptr, ATT, TMP, nullptr, nullptr, nullptr, nullptr);
    float* hout = (l==NL-1) ? (float*)d_out : HBUF;
    ln_kernel<<<dim3(1024),256,0,stream>>>(TMP, g2 + l*D, be2 + l*D, hout, HBF);
    hres = HBUF;
  }
}